// Round 1
// baseline (774.199 us; speedup 1.0000x reference)
//
#include <hip/hip_runtime.h>
#include <math.h>
#include <stdint.h>

typedef _Float16 f16;
typedef _Float16 f16x8 __attribute__((ext_vector_type(8)));
typedef float f32x16 __attribute__((ext_vector_type(16)));

// ws layout (bytes). Padded f16 layouts so LDS copies are straight memcpy.
//   uW1t: f16[128][72]  (W1^T: [n][k], k<64 valid)   18432
//   uW2t: f16[64][136]  (W2^T: [n][k], k<128 valid)  17408
//   iW1t / iW2t same                                 18432 / 17408
//   bias: f32[384] = ub1[128] ub2[64] ib1[128] ib2[64]  1536
#define WS_UW1T 0
#define WS_UW2T 18432
#define WS_IW1T 35840
#define WS_IW2T 54272
#define WS_BIAS 71680

__global__ __launch_bounds__(256) void prep_kernel(
    const float* __restrict__ uW1, const float* __restrict__ ub1,
    const float* __restrict__ uW2, const float* __restrict__ ub2,
    const float* __restrict__ iW1, const float* __restrict__ ib1,
    const float* __restrict__ iW2, const float* __restrict__ ib2,
    char* __restrict__ ws)
{
  int g = blockIdx.x * 256 + threadIdx.x;
  if (g < 8192) {                       // uW1 is [64][128] row-major -> [n][k]
    int n = g >> 6, k = g & 63;
    ((f16*)(ws + WS_UW1T))[n * 72 + k] = (f16)uW1[k * 128 + n];
  } else if (g < 16384) {               // uW2 is [128][64] -> [n][k]
    int j = g - 8192; int n = j >> 7, k = j & 127;
    ((f16*)(ws + WS_UW2T))[n * 136 + k] = (f16)uW2[k * 64 + n];
  } else if (g < 24576) {
    int j = g - 16384; int n = j >> 6, k = j & 63;
    ((f16*)(ws + WS_IW1T))[n * 72 + k] = (f16)iW1[k * 128 + n];
  } else if (g < 32768) {
    int j = g - 24576; int n = j >> 7, k = j & 127;
    ((f16*)(ws + WS_IW2T))[n * 136 + k] = (f16)iW2[k * 64 + n];
  } else if (g < 33152) {
    int j = g - 32768;
    float v = (j < 128) ? ub1[j]
            : (j < 192) ? ub2[j - 128]
            : (j < 320) ? ib1[j - 192]
                        : ib2[j - 320];
    ((float*)(ws + WS_BIAS))[j] = v;
  }
}

__device__ inline f32x16 zero16() {
  f32x16 z;
#pragma unroll
  for (int i = 0; i < 16; ++i) z[i] = 0.f;
  return z;
}

// contiguous global->LDS copy, 16B per thread per iter
__device__ inline void copy16(const char* __restrict__ g, char* s, int nbytes, int tid) {
  const uint4* gs = (const uint4*)g;
  uint4* ss = (uint4*)s;
  int n = nbytes >> 4;
  for (int j = tid; j < n; j += 256) ss[j] = gs[j];
}

// gather 128 rows (2 threads/row, 128B each) fp32 -> f16 LDS [128][72]
__device__ inline void stage_x(const int* __restrict__ ids, const float* __restrict__ table,
                               f16* sX, int base, int tid) {
  int row = tid >> 1, half = tid & 1;
  int id = ids[base + row];
  const float4* src = (const float4*)(table + (size_t)id * 64 + half * 32);
  f16* dst = sX + row * 72 + half * 32;
#pragma unroll
  for (int j = 0; j < 4; ++j) {
    float4 v0 = src[2 * j], v1 = src[2 * j + 1];
    f16x8 p;
    p[0] = (f16)v0.x; p[1] = (f16)v0.y; p[2] = (f16)v0.z; p[3] = (f16)v0.w;
    p[4] = (f16)v1.x; p[5] = (f16)v1.y; p[6] = (f16)v1.z; p[7] = (f16)v1.w;
    *(f16x8*)(dst + j * 8) = p;
  }
}

// One tower over 128 rows. On entry (post-barrier): sX = X f16[128][72],
// sW = W1t f16[128][72], sH scratch. On exit: out0/out1 = relu(h@W2+b2)
// fp32 in C-frag layout (nt=0 / nt=1), NO trailing barrier.
__device__ inline void run_tower(
    const f16* sX, f16* sW, f16* sH, const float* sB,
    const char* __restrict__ ws_w2t,
    int bias1_off, int bias2_off,
    int tid, int wave, int l31, int lhi,
    f32x16& out0, f32x16& out1)
{
  // ---- L1: [128,64] @ [64,128], 4Mt x 4Nt x 4k of 32x32x16; wave gets 2x2
  const int mt0 = (wave >> 1) * 2, nt0 = (wave & 1) * 2;
  f32x16 h00 = zero16(), h01 = zero16(), h10 = zero16(), h11 = zero16();
#pragma unroll
  for (int ks = 0; ks < 4; ++ks) {
    int ko = ks * 16 + lhi * 8;
    f16x8 a0 = *(const f16x8*)(sX + (mt0 * 32 + l31) * 72 + ko);
    f16x8 a1 = *(const f16x8*)(sX + (mt0 * 32 + 32 + l31) * 72 + ko);
    f16x8 b0 = *(const f16x8*)(sW + (nt0 * 32 + l31) * 72 + ko);
    f16x8 b1 = *(const f16x8*)(sW + (nt0 * 32 + 32 + l31) * 72 + ko);
    h00 = __builtin_amdgcn_mfma_f32_32x32x16_f16(a0, b0, h00, 0, 0, 0);
    h01 = __builtin_amdgcn_mfma_f32_32x32x16_f16(a0, b1, h01, 0, 0, 0);
    h10 = __builtin_amdgcn_mfma_f32_32x32x16_f16(a1, b0, h10, 0, 0, 0);
    h11 = __builtin_amdgcn_mfma_f32_32x32x16_f16(a1, b1, h11, 0, 0, 0);
  }
  // epilogue: +bias, relu, f16 -> sH[row][col], stride 136
  {
    float bias0 = sB[bias1_off + nt0 * 32 + l31];
    float bias1 = sB[bias1_off + nt0 * 32 + 32 + l31];
    int col0 = nt0 * 32 + l31, col1 = col0 + 32;
#pragma unroll
    for (int r = 0; r < 16; ++r) {
      int rophys = (r & 3) + 8 * (r >> 2) + 4 * lhi;   // C/D row map (m74/m101)
      int row0 = mt0 * 32 + rophys, row1 = row0 + 32;
      sH[row0 * 136 + col0] = (f16)fmaxf(h00[r] + bias0, 0.f);
      sH[row0 * 136 + col1] = (f16)fmaxf(h01[r] + bias1, 0.f);
      sH[row1 * 136 + col0] = (f16)fmaxf(h10[r] + bias0, 0.f);
      sH[row1 * 136 + col1] = (f16)fmaxf(h11[r] + bias1, 0.f);
    }
  }
  __syncthreads();                 // H complete, W1t reads complete
  copy16(ws_w2t, (char*)sW, 17408, tid);   // W2t f16[64][136] over W1t
  __syncthreads();

  // ---- L2: [128,128] @ [128,64], wave = 1 Mt x 2 Nt x 8k
  const int mt = wave;
  f32x16 v0 = zero16(), v1 = zero16();
#pragma unroll
  for (int ks = 0; ks < 8; ++ks) {
    int ko = ks * 16 + lhi * 8;
    f16x8 a  = *(const f16x8*)(sH + (mt * 32 + l31) * 136 + ko);
    f16x8 b0 = *(const f16x8*)(sW + (l31) * 136 + ko);
    f16x8 b1 = *(const f16x8*)(sW + (32 + l31) * 136 + ko);
    v0 = __builtin_amdgcn_mfma_f32_32x32x16_f16(a, b0, v0, 0, 0, 0);
    v1 = __builtin_amdgcn_mfma_f32_32x32x16_f16(a, b1, v1, 0, 0, 0);
  }
  float b20 = sB[bias2_off + l31], b21 = sB[bias2_off + 32 + l31];
#pragma unroll
  for (int r = 0; r < 16; ++r) {
    out0[r] = fmaxf(v0[r] + b20, 0.f);
    out1[r] = fmaxf(v1[r] + b21, 0.f);
  }
}

__global__ __launch_bounds__(256, 2) void TwoTowerModel_71708773974789_kernel(
    const int* __restrict__ user_ids, const int* __restrict__ item_ids,
    const float* __restrict__ user_table, const float* __restrict__ item_table,
    const char* __restrict__ ws, float* __restrict__ out)
{
  // 73216 B static LDS -> 2 blocks/CU
  __shared__ __attribute__((aligned(16))) char smem[73216];
  f16* sX = (f16*)smem;                 // X[128][72]; later U
  f16* sW = (f16*)(smem + 18432);       // W1t[128][72] / W2t[64][136]; later I
  f16* sH = (f16*)(smem + 36864);       // H[128][136]
  float* sB = (float*)(smem + 71680);   // 4 bias arrays

  const int tid = threadIdx.x;
  const int wave = tid >> 6, lane = tid & 63, l31 = lane & 31, lhi = lane >> 5;
  const int rbase = blockIdx.x * 128;

  // stage user weights + all biases + user embeddings
  copy16(ws + WS_UW1T, (char*)sW, 18432, tid);
  for (int j = tid; j < 384; j += 256) sB[j] = ((const float*)(ws + WS_BIAS))[j];
  stage_x(user_ids, user_table, sX, rbase, tid);
  __syncthreads();

  f32x16 u0, u1, i0, i1;
  run_tower(sX, sW, sH, sB, ws + WS_UW2T, 0, 128, tid, wave, l31, lhi, u0, u1);
  __syncthreads();   // user tower done; sX, sW free

  copy16(ws + WS_IW1T, (char*)sW, 18432, tid);
  stage_x(item_ids, item_table, sX, rbase, tid);
  __syncthreads();

  run_tower(sX, sW, sH, sB, ws + WS_IW2T, 192, 320, tid, wave, l31, lhi, i0, i1);
  __syncthreads();   // all item L2 reads of sW / item L1 reads of sX done

  // spill U -> sX region, I -> sW region as f16[128][72]
#pragma unroll
  for (int r = 0; r < 16; ++r) {
    int row = wave * 32 + (r & 3) + 8 * (r >> 2) + 4 * lhi;
    sX[row * 72 + l31]      = (f16)u0[r];
    sX[row * 72 + 32 + l31] = (f16)u1[r];
    sW[row * 72 + l31]      = (f16)i0[r];
    sW[row * 72 + 32 + l31] = (f16)i1[r];
  }
  __syncthreads();

  // final: per-row dot + norms (2 threads/row, 32 elems each)
  {
    int row = tid >> 1, half = tid & 1;
    const f16x8* up = (const f16x8*)(sX + row * 72 + half * 32);
    const f16x8* ip = (const f16x8*)(sW + row * 72 + half * 32);
    float sui = 0.f, suu = 0.f, sii = 0.f;
#pragma unroll
    for (int j = 0; j < 4; ++j) {
      f16x8 uv = up[j], iv = ip[j];
#pragma unroll
      for (int e = 0; e < 8; ++e) {
        float uf = (float)uv[e], vf = (float)iv[e];
        sui += uf * vf; suu += uf * uf; sii += vf * vf;
      }
    }
    sui += __shfl_xor(sui, 1);
    suu += __shfl_xor(suu, 1);
    sii += __shfl_xor(sii, 1);
    if (half == 0) {
      float nu = fmaxf(sqrtf(suu), 1e-12f);
      float nv = fmaxf(sqrtf(sii), 1e-12f);
      out[rbase + row] = sui / (nu * nv);
    }
  }
}

extern "C" void kernel_launch(void* const* d_in, const int* in_sizes, int n_in,
                              void* d_out, int out_size, void* d_ws, size_t ws_size,
                              hipStream_t stream) {
  const int*   user_ids   = (const int*)d_in[0];
  const int*   item_ids   = (const int*)d_in[1];
  const float* user_table = (const float*)d_in[2];
  const float* item_table = (const float*)d_in[3];
  const float* uW1 = (const float*)d_in[4];
  const float* ub1 = (const float*)d_in[5];
  const float* uW2 = (const float*)d_in[6];
  const float* ub2 = (const float*)d_in[7];
  const float* iW1 = (const float*)d_in[8];
  const float* ib1 = (const float*)d_in[9];
  const float* iW2 = (const float*)d_in[10];
  const float* ib2 = (const float*)d_in[11];
  char* ws = (char*)d_ws;

  prep_kernel<<<130, 256, 0, stream>>>(uW1, ub1, uW2, ub2, iW1, ib1, iW2, ib2, ws);
  int nblk = out_size / 128;   // 4096
  TwoTowerModel_71708773974789_kernel<<<nblk, 256, 0, stream>>>(
      user_ids, item_ids, user_table, item_table, ws, (float*)d_out);
}